// Round 11
// baseline (350.252 us; speedup 1.0000x reference)
//
#include <hip/hip_runtime.h>
#include <math.h>

#define NN 100000     // nodes
#define NE 1600000    // edges
#define D  128        // feature dim
#define NL 3          // layers
#define NPL (NN * 32) // u32 words per plane (dims 0-63 / 64-127, bf16x2)
#define NCH 256       // edge chunks (NE % NCH == 0 -> CH = 6250)
#define CH  (NE / NCH)
#define NBK 391       // dst buckets: dst >> 8
#define CAP 6016      // LDS colv staging capacity per bucket

typedef unsigned int u32;
typedef __attribute__((ext_vector_type(8))) short bf16x8;
typedef __attribute__((ext_vector_type(4))) float f32x4;

// ---- packed bf16x2 helpers (RNE) ----
__device__ inline float blo(u32 v) { return __uint_as_float(v << 16); }
__device__ inline float bhi(u32 v) { return __uint_as_float(v & 0xffff0000u); }
__device__ inline u32 bpack(float x, float y) {
  u32 xb = __float_as_uint(x), yb = __float_as_uint(y);
  xb = (xb + 0x7fffu + ((xb >> 16) & 1u)) >> 16;
  yb = (yb + 0x7fffu + ((yb >> 16) & 1u)) & 0xffff0000u;
  return xb | yb;
}
__device__ inline float rdlane_f(float v, int l) {
  return __uint_as_float((u32)__builtin_amdgcn_readlane((int)__float_as_uint(v), l));
}

// ================= bucketed CSR build (no global scatter) =================

__global__ __launch_bounds__(256) void k_hist(const int* __restrict__ dstv,
                                              u32* __restrict__ hist) {
  __shared__ u32 h[NBK];
  const int t = threadIdx.x, c = blockIdx.x;
  for (int b = t; b < NBK; b += 256) h[b] = 0u;
  __syncthreads();
  const int base = c * CH;
  for (int i = t; i < CH; i += 256)
    atomicAdd(&h[dstv[base + i] >> 8], 1u);
  __syncthreads();
  for (int b = t; b < NBK; b += 256) hist[b * NCH + c] = h[b];
}

__global__ __launch_bounds__(256) void k_btot(const u32* __restrict__ hist,
                                              u32* __restrict__ btot) {
  __shared__ u32 s[256];
  const int b = blockIdx.x, t = threadIdx.x;
  s[t] = hist[b * NCH + t];
  __syncthreads();
  for (int off = 128; off > 0; off >>= 1) {
    if (t < off) s[t] += s[t + off];
    __syncthreads();
  }
  if (t == 0) btot[b] = s[0];
}

__global__ __launch_bounds__(512) void k_bscan(const u32* __restrict__ btot,
                                               u32* __restrict__ bkbase) {
  __shared__ u32 s[512];
  const int t = threadIdx.x;
  const u32 v = (t < NBK) ? btot[t] : 0u;
  s[t] = v;
  __syncthreads();
  for (int off = 1; off < 512; off <<= 1) {
    const u32 x = (t >= off) ? s[t - off] : 0u;
    __syncthreads();
    s[t] += x;
    __syncthreads();
  }
  if (t < NBK) bkbase[t] = s[t] - v;
  if (t == 0) bkbase[NBK] = NE;
}

__global__ __launch_bounds__(256) void k_cscan(const u32* __restrict__ bkbase,
                                               u32* __restrict__ hist) {
  __shared__ u32 s[256];
  const int b = blockIdx.x, t = threadIdx.x;
  const u32 v = hist[b * NCH + t];
  s[t] = v;
  __syncthreads();
  for (int off = 1; off < 256; off <<= 1) {
    const u32 x = (t >= off) ? s[t - off] : 0u;
    __syncthreads();
    s[t] += x;
    __syncthreads();
  }
  hist[b * NCH + t] = bkbase[b] + s[t] - v;
}

__global__ __launch_bounds__(256) void k_scatter(const int* __restrict__ srcv,
                                                 const int* __restrict__ dstv,
                                                 const u32* __restrict__ off,
                                                 u32* __restrict__ ebuf) {
  __shared__ u32 cur[NBK];
  const int t = threadIdx.x, c = blockIdx.x;
  for (int b = t; b < NBK; b += 256) cur[b] = off[b * NCH + c];
  __syncthreads();
  const int base = c * CH;
  for (int i = t; i < CH; i += 256) {
    const int d = dstv[base + i], s = srcv[base + i];
    const u32 p = atomicAdd(&cur[d >> 8], 1u);
    ebuf[p] = (u32)s | ((u32)(d & 255) << 17);   // src:17b | dst_local:8b
  }
}

__global__ __launch_bounds__(256) void k_build(const u32* __restrict__ ebuf,
                                               const u32* __restrict__ bkbase,
                                               int* __restrict__ colv,
                                               unsigned* __restrict__ rowptr,
                                               float* __restrict__ dinv) {
  __shared__ u32 loc[256];
  __shared__ u32 curn[256];
  __shared__ u32 hl[256];
  __shared__ u32 cbuf[CAP];
  const int b = blockIdx.x, t = threadIdx.x;
  const u32 e0 = bkbase[b], e1 = bkbase[b + 1];
  const int cnt = (int)(e1 - e0);
  const int node = (b << 8) + t;

  hl[t] = 0u;
  __syncthreads();
  for (int i = t; i < cnt; i += 256)
    atomicAdd(&hl[(ebuf[e0 + i] >> 17) & 255u], 1u);
  __syncthreads();
  const u32 v = hl[t];
  loc[t] = v;
  __syncthreads();
  for (int off = 1; off < 256; off <<= 1) {
    const u32 x = (t >= off) ? loc[t - off] : 0u;
    __syncthreads();
    loc[t] += x;
    __syncthreads();
  }
  const u32 excl = loc[t] - v;
  if (node < NN) {
    rowptr[node] = e0 + excl;
    dinv[node] = rsqrtf((float)(v + 1u));     // in-degree + self-loop
  }
  if (b == NBK - 1 && t == 0) rowptr[NN] = NE;
  curn[t] = excl;
  __syncthreads();

  if (cnt <= CAP) {
    for (int i = t; i < cnt; i += 256) {
      const u32 e = ebuf[e0 + i];
      const u32 p = atomicAdd(&curn[(e >> 17) & 255u], 1u);
      cbuf[p] = e & 0x1FFFFu;
    }
    __syncthreads();
    for (int i = t; i < cnt; i += 256) colv[e0 + i] = (int)cbuf[i];
  } else {
    for (int i = t; i < cnt; i += 256) {
      const u32 e = ebuf[e0 + i];
      const u32 p = atomicAdd(&curn[(e >> 17) & 255u], 1u);
      colv[e0 + p] = (int)(e & 0x1FFFFu);
    }
  }
}

// ---------------- W (f32 [k][n]) -> bf16 W^T [n][k], packed u32 ----------------

__global__ __launch_bounds__(256) void k_wcvt(const float* __restrict__ Ws,
                                              u32* __restrict__ Wtb) {
  int i = blockIdx.x * 256 + threadIdx.x;   // l*8192 + n*64 + kw
  if (i >= NL * 128 * 64) return;
  const int l = i >> 13, rem = i & 8191, n = rem >> 6, kw = rem & 63;
  const float* Wp = Ws + l * (D * D);
  Wtb[i] = bpack(Wp[(2 * kw) * D + n], Wp[(2 * kw + 1) * D + n]);
}

// ---------------- GEMM epilogue helper (planar bf16 store) -------------------

__device__ __forceinline__ void gemm_body(const bf16x8* af, const u32* Wl,
                                          int lane, int blk, int wave,
                                          u32* __restrict__ Bb) {
  const int hi = lane >> 4, lo = lane & 15;
  f32x4 acc[8];
#pragma unroll
  for (int ct = 0; ct < 8; ++ct) acc[ct] = (f32x4){0.f, 0.f, 0.f, 0.f};

#pragma unroll
  for (int ks = 0; ks < 4; ++ks) {
#pragma unroll
    for (int ct = 0; ct < 8; ++ct) {
      const int n = ct * 16 + lo;
      const int addr = (n * 256 + ks * 64 + hi * 16) ^ ((n & 7) << 4);
      const bf16x8 bf = *(const bf16x8*)((const char*)Wl + addr);
      acc[ct] = __builtin_amdgcn_mfma_f32_16x16x32_bf16(af[ks], bf, acc[ct], 0, 0, 0);
    }
  }

  const int rbase = blk * 128 + wave * 16 + hi * 4;
  const bool even = (lane & 1) == 0;
  const int wcol = lo >> 1;
#pragma unroll
  for (int ct = 0; ct < 8; ++ct) {
    float p0 = __shfl_xor(acc[ct][0], 1, 64);
    float p1 = __shfl_xor(acc[ct][1], 1, 64);
    float p2 = __shfl_xor(acc[ct][2], 1, 64);
    float p3 = __shfl_xor(acc[ct][3], 1, 64);
    const u32 wA = even ? bpack(acc[ct][0], p0) : bpack(p2, acc[ct][2]);
    const u32 wB = even ? bpack(acc[ct][1], p1) : bpack(p3, acc[ct][3]);
    const int rA = rbase + (even ? 0 : 2);
    const size_t pb = (size_t)(ct >> 2) * NPL + (ct & 3) * 8 + wcol;
    if (rA < NN)     Bb[pb + (size_t)rA * 32] = wA;
    if (rA + 1 < NN) Bb[pb + (size_t)(rA + 1) * 32] = wB;
  }
}

// GEMM for layers >=1: A from bf16 planes.
__global__ __launch_bounds__(512, 4) void k_gemm(const u32* __restrict__ Ab,
                                                 const u32* __restrict__ Wtb,
                                                 u32* __restrict__ Bb) {
  __shared__ u32 Wl[128 * 64];   // 32 KB
  const int t = threadIdx.x;
#pragma unroll
  for (int i = 0; i < 4; ++i) {
    const int idx = (t + i * 512) * 4;
    const uint4 v = *(const uint4*)(Wtb + idx);
    const int byte = idx * 4;
    const int sw = byte ^ (((byte >> 8) & 7) << 4);
    *(uint4*)((char*)Wl + sw) = v;
  }
  __syncthreads();

  const int wave = t >> 6, lane = t & 63;
  const int hi = lane >> 4, lo = lane & 15;
  int row = blockIdx.x * 128 + wave * 16 + lo;
  const int rowc = row < NN ? row : NN - 1;

  bf16x8 af[4];
#pragma unroll
  for (int ks = 0; ks < 4; ++ks)
    af[ks] = *(const bf16x8*)(Ab + (size_t)(ks >> 1) * NPL + (size_t)rowc * 32
                              + (ks & 1) * 16 + hi * 4);
  gemm_body(af, Wl, lane, blockIdx.x, wave, Bb);
}

// GEMM for layer 0: A = x (f32), RNE-packed on the fly (== old k_cvt numerics).
__global__ __launch_bounds__(512, 4) void k_gemm0(const float* __restrict__ x,
                                                  const u32* __restrict__ Wtb,
                                                  u32* __restrict__ Bb) {
  __shared__ u32 Wl[128 * 64];
  const int t = threadIdx.x;
#pragma unroll
  for (int i = 0; i < 4; ++i) {
    const int idx = (t + i * 512) * 4;
    const uint4 v = *(const uint4*)(Wtb + idx);
    const int byte = idx * 4;
    const int sw = byte ^ (((byte >> 8) & 7) << 4);
    *(uint4*)((char*)Wl + sw) = v;
  }
  __syncthreads();

  const int wave = t >> 6, lane = t & 63;
  const int hi = lane >> 4, lo = lane & 15;
  int row = blockIdx.x * 128 + wave * 16 + lo;
  const int rowc = row < NN ? row : NN - 1;
  const float* xr = x + (size_t)rowc * D;

  bf16x8 af[4];
#pragma unroll
  for (int ks = 0; ks < 4; ++ks) {
    const int d0 = (ks * 16 + hi * 4) * 2;
    const float4 f0 = *(const float4*)(xr + d0);
    const float4 f1 = *(const float4*)(xr + d0 + 4);
    uint4 q;
    q.x = bpack(f0.x, f0.y); q.y = bpack(f0.z, f0.w);
    q.z = bpack(f1.x, f1.y); q.w = bpack(f1.z, f1.w);
    af[ks] = __builtin_bit_cast(bf16x8, q);
  }
  gemm_body(af, Wl, lane, blockIdx.x, wave, Bb);
}

// ---------------- Plane aggregation: 2 nodes/wave, 12.8 MB working set --------
// hw/ho point at the plane base; bias at the plane's 64 dims. Lanes 0-31 =
// node A, 32-63 = node B; each staged load serves one A-edge + one B-edge.

__device__ __forceinline__ void aggp_core(const u32* __restrict__ hw,
                                          const int* __restrict__ colv,
                                          const unsigned* __restrict__ rowptr,
                                          const float* __restrict__ dinv,
                                          int node, int half, int l5,
                                          float& ax, float& ay) {
  const float di = dinv[node];
  const unsigned s = rowptr[node], e = rowptr[node + 1];
  const int deg = (int)(e - s);
  const int nl = deg < 32 ? deg : 32;

  const u32 sv = hw[(size_t)node * 32 + l5];
  ax = blo(sv) * di * di;
  ay = bhi(sv) * di * di;

  int srcl = node; float wl = 0.f;
  if (l5 < nl) { srcl = colv[s + l5]; wl = dinv[srcl] * di; }

  const int nlA = __builtin_amdgcn_readlane(nl, 0);
  const int nlB = __builtin_amdgcn_readlane(nl, 32);
  int nlr = nlA > nlB ? nlA : nlB;
  nlr = (nlr + 7) & ~7;

  int q = 0;
  while (q < nlr) {
    if (q + 16 <= nlr) {
      u32 uq[16]; float wq[16];
#pragma unroll
      for (int k = 0; k < 16; ++k) {
        const int sA = __builtin_amdgcn_readlane(srcl, q + k);
        const int sB = __builtin_amdgcn_readlane(srcl, 32 + q + k);
        const float wA = rdlane_f(wl, q + k);
        const float wB = rdlane_f(wl, 32 + q + k);
        const int sk = half ? sB : sA;
        wq[k] = half ? wB : wA;
        uq[k] = hw[(size_t)sk * 32 + l5];
      }
#pragma unroll
      for (int k = 0; k < 16; ++k) {
        ax = fmaf(wq[k], blo(uq[k]), ax);
        ay = fmaf(wq[k], bhi(uq[k]), ay);
      }
      q += 16;
    } else {
      u32 uq[8]; float wq[8];
#pragma unroll
      for (int k = 0; k < 8; ++k) {
        const int sA = __builtin_amdgcn_readlane(srcl, q + k);
        const int sB = __builtin_amdgcn_readlane(srcl, 32 + q + k);
        const float wA = rdlane_f(wl, q + k);
        const float wB = rdlane_f(wl, 32 + q + k);
        const int sk = half ? sB : sA;
        wq[k] = half ? wB : wA;
        uq[k] = hw[(size_t)sk * 32 + l5];
      }
#pragma unroll
      for (int k = 0; k < 8; ++k) {
        ax = fmaf(wq[k], blo(uq[k]), ax);
        ay = fmaf(wq[k], bhi(uq[k]), ay);
      }
      q += 8;
    }
  }

  // rare tails: degree > 32 (uniform loops, inactive half weighted 0)
  const unsigned sA_u = (unsigned)__builtin_amdgcn_readlane((int)s, 0);
  const unsigned eA_u = (unsigned)__builtin_amdgcn_readlane((int)e, 0);
  const unsigned sB_u = (unsigned)__builtin_amdgcn_readlane((int)s, 32);
  const unsigned eB_u = (unsigned)__builtin_amdgcn_readlane((int)e, 32);
  const float diA = rdlane_f(di, 0);
  const float diB = rdlane_f(di, 32);
  for (unsigned j = sA_u + (unsigned)nlA; j < eA_u; ++j) {
    const int src = colv[j];
    const float w = half ? 0.f : dinv[src] * diA;
    const u32 u = hw[(size_t)src * 32 + l5];
    ax = fmaf(w, blo(u), ax); ay = fmaf(w, bhi(u), ay);
  }
  for (unsigned j = sB_u + (unsigned)nlB; j < eB_u; ++j) {
    const int src = colv[j];
    const float w = half ? dinv[src] * diB : 0.f;
    const u32 u = hw[(size_t)src * 32 + l5];
    ax = fmaf(w, blo(u), ax); ay = fmaf(w, bhi(u), ay);
  }
}

__global__ __launch_bounds__(256) void k_aggp(const u32* __restrict__ hw,
                                              const int* __restrict__ colv,
                                              const unsigned* __restrict__ rowptr,
                                              const float* __restrict__ dinv,
                                              const float* __restrict__ bias,
                                              u32* __restrict__ ho) {
  const int wv = (blockIdx.x * 256 + threadIdx.x) >> 6;
  const int lane = threadIdx.x & 63;
  const int half = lane >> 5, l5 = lane & 31;
  const int node = wv * 2 + half;
  if (node >= NN) return;

  float ax, ay;
  aggp_core(hw, colv, rowptr, dinv, node, half, l5, ax, ay);

  const float2 b = *(const float2*)&bias[l5 * 2];
  ax += b.x; ay += b.y;
  ax = ax > 0.f ? ax : 0.f;
  ay = ay > 0.f ? ay : 0.f;
  ho[(size_t)node * 32 + l5] = bpack(ax, ay);
}

// Last layer planes: fused head partial dot. plane 0 writes hb + dot, plane 1 adds.
__global__ __launch_bounds__(256) void k_aggp_head(const u32* __restrict__ hw,
                                                   const int* __restrict__ colv,
                                                   const unsigned* __restrict__ rowptr,
                                                   const float* __restrict__ dinv,
                                                   const float* __restrict__ bias,
                                                   const float* __restrict__ hW,
                                                   const float* __restrict__ hbv,
                                                   float* __restrict__ out,
                                                   int plane) {
  const int wv = (blockIdx.x * 256 + threadIdx.x) >> 6;
  const int lane = threadIdx.x & 63;
  const int half = lane >> 5, l5 = lane & 31;
  const int node = wv * 2 + half;
  if (node >= NN) return;

  float ax, ay;
  aggp_core(hw, colv, rowptr, dinv, node, half, l5, ax, ay);

  const float2 b = *(const float2*)&bias[l5 * 2];
  ax += b.x; ay += b.y;
  ax = ax > 0.f ? ax : 0.f;
  ay = ay > 0.f ? ay : 0.f;

  const float2 w = *(const float2*)&hW[l5 * 2];
  float sum = ax * w.x + ay * w.y;
#pragma unroll
  for (int off = 16; off > 0; off >>= 1) sum += __shfl_down(sum, off, 32);
  if (l5 == 0) {
    if (plane == 0) out[node] = sum + hbv[0];
    else            out[node] += sum;
  }
}

// ---------------- launch ----------------

extern "C" void kernel_launch(void* const* d_in, const int* in_sizes, int n_in,
                              void* d_out, int out_size, void* d_ws, size_t ws_size,
                              hipStream_t stream) {
  const float* x   = (const float*)d_in[0];
  const int*   ei  = (const int*)d_in[1];
  const float* Ws  = (const float*)d_in[2];
  const float* bs  = (const float*)d_in[3];
  const float* hW  = (const float*)d_in[4];
  const float* hb  = (const float*)d_in[5];
  float* out = (float*)d_out;

  char* w = (char*)d_ws;
  u32*      bufA    = (u32*)w;      w += (size_t)NN * 64 * 4;        // 25.6 MB (h, 2 planes)
  u32*      bufB    = (u32*)w;      w += (size_t)NN * 64 * 4;        // 25.6 MB (hw, 2 planes)
  int*      colv    = (int*)w;      w += (size_t)NE * 4;             // 6.4 MB
  u32*      ebuf    = (u32*)w;      w += (size_t)NE * 4;             // 6.4 MB
  u32*      hist    = (u32*)w;      w += (size_t)NBK * NCH * 4;      // 400 KB
  u32*      Wtb     = (u32*)w;      w += (size_t)NL * 128 * 64 * 4;  // 96 KB
  unsigned* rowptr  = (unsigned*)w; w += (size_t)(NN + 16) * 4;
  float*    dinv    = (float*)w;    w += (size_t)NN * 4;
  u32*      btot    = (u32*)w;      w += (size_t)(NBK + 8) * 4;
  u32*      bkbase  = (u32*)w;      w += (size_t)(NBK + 8) * 4;

  const int* srcv = ei;
  const int* dstv = ei + NE;

  // ---- CSR build (no global scatter) ----
  k_hist   <<<NCH, 256, 0, stream>>>(dstv, hist);
  k_btot   <<<NBK, 256, 0, stream>>>(hist, btot);
  k_bscan  <<<1,   512, 0, stream>>>(btot, bkbase);
  k_cscan  <<<NBK, 256, 0, stream>>>(bkbase, hist);
  k_scatter<<<NCH, 256, 0, stream>>>(srcv, dstv, hist, ebuf);
  k_build  <<<NBK, 256, 0, stream>>>(ebuf, bkbase, colv, rowptr, dinv);

  k_wcvt<<<(NL * 128 * 64 + 255) / 256, 256, 0, stream>>>(Ws, Wtb);

  const int GB = (NN + 127) / 128;   // GEMM blocks
  const int AB = (NN + 7) / 8;       // agg blocks: 4 waves x 2 nodes = 8 nodes/block

  for (int l = 0; l < NL; ++l) {
    if (l == 0)
      k_gemm0<<<GB, 512, 0, stream>>>(x, Wtb, bufB);
    else
      k_gemm<<<GB, 512, 0, stream>>>(bufA, Wtb + (size_t)l * 128 * 64, bufB);

    if (l < NL - 1) {
      for (int p = 0; p < 2; ++p)
        k_aggp<<<AB, 256, 0, stream>>>(bufB + (size_t)p * NPL, colv, rowptr, dinv,
                                       bs + (size_t)l * D + p * 64,
                                       bufA + (size_t)p * NPL);
    } else {
      for (int p = 0; p < 2; ++p)
        k_aggp_head<<<AB, 256, 0, stream>>>(bufB + (size_t)p * NPL, colv, rowptr, dinv,
                                            bs + (size_t)l * D + p * 64,
                                            hW + p * 64, hb, out, p);
    }
  }
}

// Round 12
// 276.179 us; speedup vs baseline: 1.2682x; 1.2682x over previous
//
#include <hip/hip_runtime.h>
#include <math.h>

#define NN 100000     // nodes
#define NE 1600000    // edges
#define D  128        // feature dim
#define NW 64         // u32 words per row (D/2 packed bf16x2)
#define NL 3          // layers
#define NCH 256       // edge chunks (NE % NCH == 0 -> CH = 6250)
#define CH  (NE / NCH)
#define NBK 391       // dst buckets: dst >> 8
#define CAP 6016      // LDS colv staging capacity per bucket

typedef unsigned int u32;
typedef __attribute__((ext_vector_type(8))) short bf16x8;
typedef __attribute__((ext_vector_type(4))) float f32x4;

// ---- packed bf16x2 helpers (RNE) ----
__device__ inline float blo(u32 v) { return __uint_as_float(v << 16); }
__device__ inline float bhi(u32 v) { return __uint_as_float(v & 0xffff0000u); }
__device__ inline u32 bpack(float x, float y) {
  u32 xb = __float_as_uint(x), yb = __float_as_uint(y);
  xb = (xb + 0x7fffu + ((xb >> 16) & 1u)) >> 16;
  yb = (yb + 0x7fffu + ((yb >> 16) & 1u)) & 0xffff0000u;
  return xb | yb;
}

// ================= bucketed CSR build (no global scatter) =================

__global__ __launch_bounds__(256) void k_hist(const int* __restrict__ dstv,
                                              u32* __restrict__ hist) {
  __shared__ u32 h[NBK];
  const int t = threadIdx.x, c = blockIdx.x;
  for (int b = t; b < NBK; b += 256) h[b] = 0u;
  __syncthreads();
  const int base = c * CH;
  for (int i = t; i < CH; i += 256)
    atomicAdd(&h[dstv[base + i] >> 8], 1u);
  __syncthreads();
  for (int b = t; b < NBK; b += 256) hist[b * NCH + c] = h[b];
}

__global__ __launch_bounds__(256) void k_btot(const u32* __restrict__ hist,
                                              u32* __restrict__ btot) {
  __shared__ u32 s[256];
  const int b = blockIdx.x, t = threadIdx.x;
  s[t] = hist[b * NCH + t];
  __syncthreads();
  for (int off = 128; off > 0; off >>= 1) {
    if (t < off) s[t] += s[t + off];
    __syncthreads();
  }
  if (t == 0) btot[b] = s[0];
}

__global__ __launch_bounds__(512) void k_bscan(const u32* __restrict__ btot,
                                               u32* __restrict__ bkbase) {
  __shared__ u32 s[512];
  const int t = threadIdx.x;
  const u32 v = (t < NBK) ? btot[t] : 0u;
  s[t] = v;
  __syncthreads();
  for (int off = 1; off < 512; off <<= 1) {
    const u32 x = (t >= off) ? s[t - off] : 0u;
    __syncthreads();
    s[t] += x;
    __syncthreads();
  }
  if (t < NBK) bkbase[t] = s[t] - v;
  if (t == 0) bkbase[NBK] = NE;
}

__global__ __launch_bounds__(256) void k_cscan(const u32* __restrict__ bkbase,
                                               u32* __restrict__ hist) {
  __shared__ u32 s[256];
  const int b = blockIdx.x, t = threadIdx.x;
  const u32 v = hist[b * NCH + t];
  s[t] = v;
  __syncthreads();
  for (int off = 1; off < 256; off <<= 1) {
    const u32 x = (t >= off) ? s[t - off] : 0u;
    __syncthreads();
    s[t] += x;
    __syncthreads();
  }
  hist[b * NCH + t] = bkbase[b] + s[t] - v;
}

__global__ __launch_bounds__(256) void k_scatter(const int* __restrict__ srcv,
                                                 const int* __restrict__ dstv,
                                                 const u32* __restrict__ off,
                                                 u32* __restrict__ ebuf) {
  __shared__ u32 cur[NBK];
  const int t = threadIdx.x, c = blockIdx.x;
  for (int b = t; b < NBK; b += 256) cur[b] = off[b * NCH + c];
  __syncthreads();
  const int base = c * CH;
  for (int i = t; i < CH; i += 256) {
    const int d = dstv[base + i], s = srcv[base + i];
    const u32 p = atomicAdd(&cur[d >> 8], 1u);
    ebuf[p] = (u32)s | ((u32)(d & 255) << 17);   // src:17b | dst_local:8b
  }
}

__global__ __launch_bounds__(256) void k_build(const u32* __restrict__ ebuf,
                                               const u32* __restrict__ bkbase,
                                               int* __restrict__ colv,
                                               unsigned* __restrict__ rowptr,
                                               float* __restrict__ dinv) {
  __shared__ u32 loc[256];
  __shared__ u32 curn[256];
  __shared__ u32 hl[256];
  __shared__ u32 cbuf[CAP];
  const int b = blockIdx.x, t = threadIdx.x;
  const u32 e0 = bkbase[b], e1 = bkbase[b + 1];
  const int cnt = (int)(e1 - e0);
  const int node = (b << 8) + t;

  hl[t] = 0u;
  __syncthreads();
  for (int i = t; i < cnt; i += 256)
    atomicAdd(&hl[(ebuf[e0 + i] >> 17) & 255u], 1u);
  __syncthreads();
  const u32 v = hl[t];
  loc[t] = v;
  __syncthreads();
  for (int off = 1; off < 256; off <<= 1) {
    const u32 x = (t >= off) ? loc[t - off] : 0u;
    __syncthreads();
    loc[t] += x;
    __syncthreads();
  }
  const u32 excl = loc[t] - v;
  if (node < NN) {
    rowptr[node] = e0 + excl;
    dinv[node] = rsqrtf((float)(v + 1u));     // in-degree + self-loop
  }
  if (b == NBK - 1 && t == 0) rowptr[NN] = NE;
  curn[t] = excl;
  __syncthreads();

  if (cnt <= CAP) {
    for (int i = t; i < cnt; i += 256) {
      const u32 e = ebuf[e0 + i];
      const u32 p = atomicAdd(&curn[(e >> 17) & 255u], 1u);
      cbuf[p] = e & 0x1FFFFu;
    }
    __syncthreads();
    for (int i = t; i < cnt; i += 256) colv[e0 + i] = (int)cbuf[i];
  } else {
    for (int i = t; i < cnt; i += 256) {
      const u32 e = ebuf[e0 + i];
      const u32 p = atomicAdd(&curn[(e >> 17) & 255u], 1u);
      colv[e0 + p] = (int)(e & 0x1FFFFu);
    }
  }
}

// ---------------- W (f32 [k][n]) -> bf16 W^T [n][k], packed u32 ----------------

__global__ __launch_bounds__(256) void k_wcvt(const float* __restrict__ Ws,
                                              u32* __restrict__ Wtb) {
  int i = blockIdx.x * 256 + threadIdx.x;   // l*8192 + n*64 + kw
  if (i >= NL * 128 * 64) return;
  const int l = i >> 13, rem = i & 8191, n = rem >> 6, kw = rem & 63;
  const float* Wp = Ws + l * (D * D);
  Wtb[i] = bpack(Wp[(2 * kw) * D + n], Wp[(2 * kw + 1) * D + n]);
}

// ---------------- GEMM: hw = h @ W  (bf16 MFMA, W^T in swizzled LDS) ----------
// 512 threads (8 waves), 128 rows/block; NW=64 row-contiguous bf16x2 output.

__device__ __forceinline__ void gemm_body(const bf16x8* af, const u32* Wl,
                                          int lane, int blk, int wave,
                                          u32* __restrict__ Bb) {
  const int hi = lane >> 4, lo = lane & 15;
  f32x4 acc[8];
#pragma unroll
  for (int ct = 0; ct < 8; ++ct) acc[ct] = (f32x4){0.f, 0.f, 0.f, 0.f};

#pragma unroll
  for (int ks = 0; ks < 4; ++ks) {
#pragma unroll
    for (int ct = 0; ct < 8; ++ct) {
      const int n = ct * 16 + lo;
      const int addr = (n * 256 + ks * 64 + hi * 16) ^ ((n & 7) << 4);
      const bf16x8 bf = *(const bf16x8*)((const char*)Wl + addr);
      acc[ct] = __builtin_amdgcn_mfma_f32_16x16x32_bf16(af[ks], bf, acc[ct], 0, 0, 0);
    }
  }

  const int rbase = blk * 128 + wave * 16 + hi * 4;
  const bool even = (lane & 1) == 0;
  const int wcol = lo >> 1;
#pragma unroll
  for (int ct = 0; ct < 8; ++ct) {
    float p0 = __shfl_xor(acc[ct][0], 1, 64);
    float p1 = __shfl_xor(acc[ct][1], 1, 64);
    float p2 = __shfl_xor(acc[ct][2], 1, 64);
    float p3 = __shfl_xor(acc[ct][3], 1, 64);
    const u32 wA = even ? bpack(acc[ct][0], p0) : bpack(p2, acc[ct][2]);
    const u32 wB = even ? bpack(acc[ct][1], p1) : bpack(p3, acc[ct][3]);
    const int rA = rbase + (even ? 0 : 2);
    if (rA < NN)     Bb[(size_t)rA * NW + ct * 8 + wcol] = wA;
    if (rA + 1 < NN) Bb[(size_t)(rA + 1) * NW + ct * 8 + wcol] = wB;
  }
}

// Layers >= 1: A from bf16 buffer.
__global__ __launch_bounds__(512, 4) void k_gemm(const u32* __restrict__ Ab,
                                                 const u32* __restrict__ Wtb,
                                                 u32* __restrict__ Bb) {
  __shared__ u32 Wl[128 * 64];   // 32 KB
  const int t = threadIdx.x;
#pragma unroll
  for (int i = 0; i < 4; ++i) {
    const int idx = (t + i * 512) * 4;
    const uint4 v = *(const uint4*)(Wtb + idx);
    const int byte = idx * 4;
    const int sw = byte ^ (((byte >> 8) & 7) << 4);
    *(uint4*)((char*)Wl + sw) = v;
  }
  __syncthreads();

  const int wave = t >> 6, lane = t & 63;
  const int hi = lane >> 4, lo = lane & 15;
  int row = blockIdx.x * 128 + wave * 16 + lo;
  const int rowc = row < NN ? row : NN - 1;

  bf16x8 af[4];
#pragma unroll
  for (int ks = 0; ks < 4; ++ks)
    af[ks] = *(const bf16x8*)(Ab + (size_t)rowc * NW + ks * 16 + hi * 4);
  gemm_body(af, Wl, lane, blockIdx.x, wave, Bb);
}

// Layer 0: A = x (f32), RNE-packed on the fly (numerics == cvt + gemm).
__global__ __launch_bounds__(512, 4) void k_gemm0(const float* __restrict__ x,
                                                  const u32* __restrict__ Wtb,
                                                  u32* __restrict__ Bb) {
  __shared__ u32 Wl[128 * 64];
  const int t = threadIdx.x;
#pragma unroll
  for (int i = 0; i < 4; ++i) {
    const int idx = (t + i * 512) * 4;
    const uint4 v = *(const uint4*)(Wtb + idx);
    const int byte = idx * 4;
    const int sw = byte ^ (((byte >> 8) & 7) << 4);
    *(uint4*)((char*)Wl + sw) = v;
  }
  __syncthreads();

  const int wave = t >> 6, lane = t & 63;
  const int hi = lane >> 4, lo = lane & 15;
  int row = blockIdx.x * 128 + wave * 16 + lo;
  const int rowc = row < NN ? row : NN - 1;
  const float* xr = x + (size_t)rowc * D;

  bf16x8 af[4];
#pragma unroll
  for (int ks = 0; ks < 4; ++ks) {
    const int d0 = (ks * 16 + hi * 4) * 2;
    const float4 f0 = *(const float4*)(xr + d0);
    const float4 f1 = *(const float4*)(xr + d0 + 4);
    uint4 q;
    q.x = bpack(f0.x, f0.y); q.y = bpack(f0.z, f0.w);
    q.z = bpack(f1.x, f1.y); q.w = bpack(f1.z, f1.w);
    af[ks] = __builtin_bit_cast(bf16x8, q);
  }
  gemm_body(af, Wl, lane, blockIdx.x, wave, Bb);
}

// ---------------- Aggregation: one wave/node, 16-deep SGPR-broadcast gather ----

__device__ __forceinline__ void agg_core(const u32* __restrict__ hwb,
                                         const int* __restrict__ colv,
                                         const unsigned* __restrict__ rowptr,
                                         const float* __restrict__ dinv,
                                         int wid, int lane,
                                         float& ax, float& ay) {
  const float di = dinv[wid];
  const u32 sv = hwb[(size_t)wid * NW + lane];
  ax = blo(sv) * di * di;
  ay = bhi(sv) * di * di;

  const unsigned s = rowptr[wid], e = rowptr[wid + 1];
  const int deg = (int)(e - s);
  const int nl = deg < 64 ? deg : 64;
  const int nlr = (nl + 7) & ~7;       // pad to x8; pad lanes have w=0

  int srcl = wid;
  float wl = 0.f;
  if (lane < nl) {
    srcl = colv[s + lane];
    wl = dinv[srcl] * di;
  }

  int q = 0;
  while (q < nlr) {
    if (q + 16 <= nlr) {
      int sq[16]; float wq[16]; u32 uq[16];
#pragma unroll
      for (int k = 0; k < 16; ++k) {
        sq[k] = __builtin_amdgcn_readlane(srcl, q + k);
        wq[k] = __uint_as_float((u32)__builtin_amdgcn_readlane((int)__float_as_uint(wl), q + k));
      }
#pragma unroll
      for (int k = 0; k < 16; ++k) uq[k] = hwb[(size_t)sq[k] * NW + lane];
#pragma unroll
      for (int k = 0; k < 16; ++k) {
        ax = fmaf(wq[k], blo(uq[k]), ax);
        ay = fmaf(wq[k], bhi(uq[k]), ay);
      }
      q += 16;
    } else {
      int sq[8]; float wq[8]; u32 uq[8];
#pragma unroll
      for (int k = 0; k < 8; ++k) {
        sq[k] = __builtin_amdgcn_readlane(srcl, q + k);
        wq[k] = __uint_as_float((u32)__builtin_amdgcn_readlane((int)__float_as_uint(wl), q + k));
      }
#pragma unroll
      for (int k = 0; k < 8; ++k) uq[k] = hwb[(size_t)sq[k] * NW + lane];
#pragma unroll
      for (int k = 0; k < 8; ++k) {
        ax = fmaf(wq[k], blo(uq[k]), ax);
        ay = fmaf(wq[k], bhi(uq[k]), ay);
      }
      q += 8;
    }
  }
  // rare tail: degree > 64
  for (unsigned j = s + (unsigned)nl; j < e; ++j) {
    const int src = colv[j];
    const float w = dinv[src] * di;
    const u32 u = hwb[(size_t)src * NW + lane];
    ax = fmaf(w, blo(u), ax);
    ay = fmaf(w, bhi(u), ay);
  }
}

__global__ __launch_bounds__(256) void k_agg(const u32* __restrict__ hwb,
                                             const int* __restrict__ colv,
                                             const unsigned* __restrict__ rowptr,
                                             const float* __restrict__ dinv,
                                             const float* __restrict__ bias,
                                             u32* __restrict__ hob) {
  const int widt = (blockIdx.x * 256 + threadIdx.x) >> 6;
  if (widt >= NN) return;
  const int wid = __builtin_amdgcn_readfirstlane(widt);
  const int lane = threadIdx.x & 63;

  float ax, ay;
  agg_core(hwb, colv, rowptr, dinv, wid, lane, ax, ay);

  const float2 b = *(const float2*)&bias[lane * 2];
  ax += b.x; ay += b.y;
  ax = ax > 0.f ? ax : 0.f;
  ay = ay > 0.f ? ay : 0.f;
  hob[(size_t)wid * NW + lane] = bpack(ax, ay);
}

// Last layer: fused head GEMV, f32 accum, no bf16 store of final hidden.
__global__ __launch_bounds__(256) void k_agg_head(const u32* __restrict__ hwb,
                                                  const int* __restrict__ colv,
                                                  const unsigned* __restrict__ rowptr,
                                                  const float* __restrict__ dinv,
                                                  const float* __restrict__ bias,
                                                  const float* __restrict__ hW,
                                                  const float* __restrict__ hbv,
                                                  float* __restrict__ out) {
  const int widt = (blockIdx.x * 256 + threadIdx.x) >> 6;
  if (widt >= NN) return;
  const int wid = __builtin_amdgcn_readfirstlane(widt);
  const int lane = threadIdx.x & 63;

  float ax, ay;
  agg_core(hwb, colv, rowptr, dinv, wid, lane, ax, ay);

  const float2 b = *(const float2*)&bias[lane * 2];
  ax += b.x; ay += b.y;
  ax = ax > 0.f ? ax : 0.f;
  ay = ay > 0.f ? ay : 0.f;

  const float2 w = *(const float2*)&hW[lane * 2];
  float sum = ax * w.x + ay * w.y;
#pragma unroll
  for (int off = 32; off > 0; off >>= 1) sum += __shfl_down(sum, off, 64);
  if (lane == 0) out[wid] = sum + hbv[0];
}

// ---------------- launch ----------------

extern "C" void kernel_launch(void* const* d_in, const int* in_sizes, int n_in,
                              void* d_out, int out_size, void* d_ws, size_t ws_size,
                              hipStream_t stream) {
  const float* x   = (const float*)d_in[0];
  const int*   ei  = (const int*)d_in[1];
  const float* Ws  = (const float*)d_in[2];
  const float* bs  = (const float*)d_in[3];
  const float* hW  = (const float*)d_in[4];
  const float* hb  = (const float*)d_in[5];
  float* out = (float*)d_out;

  char* w = (char*)d_ws;
  u32*      bufA    = (u32*)w;      w += (size_t)NN * NW * 4;        // 25.6 MB (h)
  u32*      bufB    = (u32*)w;      w += (size_t)NN * NW * 4;        // 25.6 MB (hw)
  int*      colv    = (int*)w;      w += (size_t)NE * 4;             // 6.4 MB
  u32*      ebuf    = (u32*)w;      w += (size_t)NE * 4;             // 6.4 MB
  u32*      hist    = (u32*)w;      w += (size_t)NBK * NCH * 4;      // 400 KB
  u32*      Wtb     = (u32*)w;      w += (size_t)NL * 128 * 64 * 4;  // 96 KB
  unsigned* rowptr  = (unsigned*)w; w += (size_t)(NN + 16) * 4;
  float*    dinv    = (float*)w;    w += (size_t)NN * 4;
  u32*      btot    = (u32*)w;      w += (size_t)(NBK + 8) * 4;
  u32*      bkbase  = (u32*)w;      w += (size_t)(NBK + 8) * 4;

  const int* srcv = ei;
  const int* dstv = ei + NE;

  // ---- CSR build (no global scatter) ----
  k_hist   <<<NCH, 256, 0, stream>>>(dstv, hist);
  k_btot   <<<NBK, 256, 0, stream>>>(hist, btot);
  k_bscan  <<<1,   512, 0, stream>>>(btot, bkbase);
  k_cscan  <<<NBK, 256, 0, stream>>>(bkbase, hist);
  k_scatter<<<NCH, 256, 0, stream>>>(srcv, dstv, hist, ebuf);
  k_build  <<<NBK, 256, 0, stream>>>(ebuf, bkbase, colv, rowptr, dinv);

  k_wcvt<<<(NL * 128 * 64 + 255) / 256, 256, 0, stream>>>(Ws, Wtb);

  const int GB = (NN + 127) / 128;   // GEMM blocks (512 thr)
  const int AB = (NN + 3) / 4;       // agg blocks: 4 waves x 1 node

  for (int l = 0; l < NL; ++l) {
    if (l == 0)
      k_gemm0<<<GB, 512, 0, stream>>>(x, Wtb, bufB);
    else
      k_gemm<<<GB, 512, 0, stream>>>(bufA, Wtb + (size_t)l * 128 * 64, bufB);

    if (l < NL - 1) {
      k_agg<<<AB, 256, 0, stream>>>(bufB, colv, rowptr, dinv,
                                    bs + (size_t)l * D, bufA);
    } else {
      k_agg_head<<<AB, 256, 0, stream>>>(bufB, colv, rowptr, dinv,
                                         bs + (size_t)l * D, hW, hb, out);
    }
  }
}

// Round 13
// 270.677 us; speedup vs baseline: 1.2940x; 1.0203x over previous
//
#include <hip/hip_runtime.h>
#include <math.h>

#define NN 100000     // nodes
#define NE 1600000    // edges
#define D  128        // feature dim
#define NW 64         // u32 words per row (D/2 packed bf16x2)
#define NL 3          // layers
#define NCH 250       // edge chunks (NE = 250 * 6400; CH % 8 == 0 for int4x2 loads)
#define CH  (NE / NCH)
#define NBK 391       // dst buckets: dst >> 8
#define CAP 6016      // LDS edge staging capacity per bucket (mean 4096, sd ~64)

typedef unsigned int u32;
typedef __attribute__((ext_vector_type(8))) short bf16x8;
typedef __attribute__((ext_vector_type(4))) float f32x4;

// ---- packed bf16x2 helpers (RNE) ----
__device__ inline float blo(u32 v) { return __uint_as_float(v << 16); }
__device__ inline float bhi(u32 v) { return __uint_as_float(v & 0xffff0000u); }
__device__ inline u32 bpack(float x, float y) {
  u32 xb = __float_as_uint(x), yb = __float_as_uint(y);
  xb = (xb + 0x7fffu + ((xb >> 16) & 1u)) >> 16;
  yb = (yb + 0x7fffu + ((yb >> 16) & 1u)) & 0xffff0000u;
  return xb | yb;
}

// ================= bucketed CSR build (no global scatter) =================

// Phase A: per-chunk histogram of dst>>8 into LDS; int4x2 edge loads.
__global__ __launch_bounds__(256) void k_hist(const int* __restrict__ dstv,
                                              u32* __restrict__ hist) {
  __shared__ u32 h[NBK];
  const int t = threadIdx.x, c = blockIdx.x;
  for (int b = t; b < NBK; b += 256) h[b] = 0u;
  __syncthreads();
  const int base = c * CH;
  for (int i = t * 8; i + 8 <= CH; i += 2048) {
    const int4 d0 = *(const int4*)(dstv + base + i);
    const int4 d1 = *(const int4*)(dstv + base + i + 4);
    atomicAdd(&h[d0.x >> 8], 1u); atomicAdd(&h[d0.y >> 8], 1u);
    atomicAdd(&h[d0.z >> 8], 1u); atomicAdd(&h[d0.w >> 8], 1u);
    atomicAdd(&h[d1.x >> 8], 1u); atomicAdd(&h[d1.y >> 8], 1u);
    atomicAdd(&h[d1.z >> 8], 1u); atomicAdd(&h[d1.w >> 8], 1u);
  }
  __syncthreads();
  for (int b = t; b < NBK; b += 256) hist[b * NCH + c] = h[b];
}

// Phase B1: per-bucket totals.
__global__ __launch_bounds__(256) void k_btot(const u32* __restrict__ hist,
                                              u32* __restrict__ btot) {
  __shared__ u32 s[256];
  const int b = blockIdx.x, t = threadIdx.x;
  s[t] = (t < NCH) ? hist[b * NCH + t] : 0u;
  __syncthreads();
  for (int off = 128; off > 0; off >>= 1) {
    if (t < off) s[t] += s[t + off];
    __syncthreads();
  }
  if (t == 0) btot[b] = s[0];
}

// Phase B2: exclusive scan of 391 bucket totals.
__global__ __launch_bounds__(512) void k_bscan(const u32* __restrict__ btot,
                                               u32* __restrict__ bkbase) {
  __shared__ u32 s[512];
  const int t = threadIdx.x;
  const u32 v = (t < NBK) ? btot[t] : 0u;
  s[t] = v;
  __syncthreads();
  for (int off = 1; off < 512; off <<= 1) {
    const u32 x = (t >= off) ? s[t - off] : 0u;
    __syncthreads();
    s[t] += x;
    __syncthreads();
  }
  if (t < NBK) bkbase[t] = s[t] - v;
  if (t == 0) bkbase[NBK] = NE;
}

// Phase B3: per-bucket exclusive scan over chunk counts -> absolute offsets.
__global__ __launch_bounds__(256) void k_cscan(const u32* __restrict__ bkbase,
                                               u32* __restrict__ hist) {
  __shared__ u32 s[256];
  const int b = blockIdx.x, t = threadIdx.x;
  const u32 v = (t < NCH) ? hist[b * NCH + t] : 0u;
  s[t] = v;
  __syncthreads();
  for (int off = 1; off < 256; off <<= 1) {
    const u32 x = (t >= off) ? s[t - off] : 0u;
    __syncthreads();
    s[t] += x;
    __syncthreads();
  }
  if (t < NCH) hist[b * NCH + t] = bkbase[b] + s[t] - v;
}

// Phase C: scatter edges into bucket-major order; int4x2 edge loads.
__global__ __launch_bounds__(256) void k_scatter(const int* __restrict__ srcv,
                                                 const int* __restrict__ dstv,
                                                 const u32* __restrict__ off,
                                                 u32* __restrict__ ebuf) {
  __shared__ u32 cur[NBK];
  const int t = threadIdx.x, c = blockIdx.x;
  for (int b = t; b < NBK; b += 256) cur[b] = off[b * NCH + c];
  __syncthreads();
  const int base = c * CH;
  for (int i = t * 8; i + 8 <= CH; i += 2048) {
    const int4 d0 = *(const int4*)(dstv + base + i);
    const int4 d1 = *(const int4*)(dstv + base + i + 4);
    const int4 s0 = *(const int4*)(srcv + base + i);
    const int4 s1 = *(const int4*)(srcv + base + i + 4);
    const int ds[8] = {d0.x, d0.y, d0.z, d0.w, d1.x, d1.y, d1.z, d1.w};
    const int ss[8] = {s0.x, s0.y, s0.z, s0.w, s1.x, s1.y, s1.z, s1.w};
#pragma unroll
    for (int q = 0; q < 8; ++q) {
      const u32 p = atomicAdd(&cur[ds[q] >> 8], 1u);
      ebuf[p] = (u32)ss[q] | ((u32)(ds[q] & 255) << 17);   // src:17b | dst_local:8b
    }
  }
}

// Phase D: one block per bucket. Stage bucket edges in LDS once; LDS
// node-histogram + scan -> rowptr + dinv; LDS scatter -> coalesced colv write.
__global__ __launch_bounds__(256) void k_build(const u32* __restrict__ ebuf,
                                               const u32* __restrict__ bkbase,
                                               int* __restrict__ colv,
                                               unsigned* __restrict__ rowptr,
                                               float* __restrict__ dinv) {
  __shared__ u32 ebl[CAP];
  __shared__ u32 cbuf[CAP];
  __shared__ u32 loc[256];
  __shared__ u32 curn[256];
  __shared__ u32 hl[256];
  const int b = blockIdx.x, t = threadIdx.x;
  const u32 e0 = bkbase[b], e1 = bkbase[b + 1];
  const int cnt = (int)(e1 - e0);
  const int node = (b << 8) + t;

  hl[t] = 0u;
  const bool fits = (cnt <= CAP);
  if (fits) {
    for (int i = t; i < cnt; i += 256) ebl[i] = ebuf[e0 + i];
  }
  __syncthreads();

  if (fits) {
    for (int i = t; i < cnt; i += 256)
      atomicAdd(&hl[(ebl[i] >> 17) & 255u], 1u);
  } else {
    for (int i = t; i < cnt; i += 256)
      atomicAdd(&hl[(ebuf[e0 + i] >> 17) & 255u], 1u);
  }
  __syncthreads();

  const u32 v = hl[t];
  loc[t] = v;
  __syncthreads();
  for (int off = 1; off < 256; off <<= 1) {
    const u32 x = (t >= off) ? loc[t - off] : 0u;
    __syncthreads();
    loc[t] += x;
    __syncthreads();
  }
  const u32 excl = loc[t] - v;
  if (node < NN) {
    rowptr[node] = e0 + excl;
    dinv[node] = rsqrtf((float)(v + 1u));     // in-degree + self-loop
  }
  if (b == NBK - 1 && t == 0) rowptr[NN] = NE;
  curn[t] = excl;
  __syncthreads();

  if (fits) {
    for (int i = t; i < cnt; i += 256) {
      const u32 e = ebl[i];
      const u32 p = atomicAdd(&curn[(e >> 17) & 255u], 1u);
      cbuf[p] = e & 0x1FFFFu;
    }
    __syncthreads();
    for (int i = t; i < cnt; i += 256) colv[e0 + i] = (int)cbuf[i];
  } else {      // statistically unreachable safety net
    for (int i = t; i < cnt; i += 256) {
      const u32 e = ebuf[e0 + i];
      const u32 p = atomicAdd(&curn[(e >> 17) & 255u], 1u);
      colv[e0 + p] = (int)(e & 0x1FFFFu);
    }
  }
}

// ---------------- W (f32 [k][n]) -> bf16 W^T [n][k], packed u32 ----------------

__global__ __launch_bounds__(256) void k_wcvt(const float* __restrict__ Ws,
                                              u32* __restrict__ Wtb) {
  int i = blockIdx.x * 256 + threadIdx.x;   // l*8192 + n*64 + kw
  if (i >= NL * 128 * 64) return;
  const int l = i >> 13, rem = i & 8191, n = rem >> 6, kw = rem & 63;
  const float* Wp = Ws + l * (D * D);
  Wtb[i] = bpack(Wp[(2 * kw) * D + n], Wp[(2 * kw + 1) * D + n]);
}

// ---------------- GEMM: hw = h @ W  (bf16 MFMA, W^T in swizzled LDS) ----------
// 512 threads (8 waves), 128 rows/block; NW=64 row-contiguous bf16x2 output.

__device__ __forceinline__ void gemm_body(const bf16x8* af, const u32* Wl,
                                          int lane, int blk, int wave,
                                          u32* __restrict__ Bb) {
  const int hi = lane >> 4, lo = lane & 15;
  f32x4 acc[8];
#pragma unroll
  for (int ct = 0; ct < 8; ++ct) acc[ct] = (f32x4){0.f, 0.f, 0.f, 0.f};

#pragma unroll
  for (int ks = 0; ks < 4; ++ks) {
#pragma unroll
    for (int ct = 0; ct < 8; ++ct) {
      const int n = ct * 16 + lo;
      const int addr = (n * 256 + ks * 64 + hi * 16) ^ ((n & 7) << 4);
      const bf16x8 bf = *(const bf16x8*)((const char*)Wl + addr);
      acc[ct] = __builtin_amdgcn_mfma_f32_16x16x32_bf16(af[ks], bf, acc[ct], 0, 0, 0);
    }
  }

  const int rbase = blk * 128 + wave * 16 + hi * 4;
  const bool even = (lane & 1) == 0;
  const int wcol = lo >> 1;
#pragma unroll
  for (int ct = 0; ct < 8; ++ct) {
    float p0 = __shfl_xor(acc[ct][0], 1, 64);
    float p1 = __shfl_xor(acc[ct][1], 1, 64);
    float p2 = __shfl_xor(acc[ct][2], 1, 64);
    float p3 = __shfl_xor(acc[ct][3], 1, 64);
    const u32 wA = even ? bpack(acc[ct][0], p0) : bpack(p2, acc[ct][2]);
    const u32 wB = even ? bpack(acc[ct][1], p1) : bpack(p3, acc[ct][3]);
    const int rA = rbase + (even ? 0 : 2);
    if (rA < NN)     Bb[(size_t)rA * NW + ct * 8 + wcol] = wA;
    if (rA + 1 < NN) Bb[(size_t)(rA + 1) * NW + ct * 8 + wcol] = wB;
  }
}

// Layers >= 1: A from bf16 buffer.
__global__ __launch_bounds__(512, 4) void k_gemm(const u32* __restrict__ Ab,
                                                 const u32* __restrict__ Wtb,
                                                 u32* __restrict__ Bb) {
  __shared__ u32 Wl[128 * 64];   // 32 KB
  const int t = threadIdx.x;
#pragma unroll
  for (int i = 0; i < 4; ++i) {
    const int idx = (t + i * 512) * 4;
    const uint4 v = *(const uint4*)(Wtb + idx);
    const int byte = idx * 4;
    const int sw = byte ^ (((byte >> 8) & 7) << 4);
    *(uint4*)((char*)Wl + sw) = v;
  }
  __syncthreads();

  const int wave = t >> 6, lane = t & 63;
  const int hi = lane >> 4, lo = lane & 15;
  int row = blockIdx.x * 128 + wave * 16 + lo;
  const int rowc = row < NN ? row : NN - 1;

  bf16x8 af[4];
#pragma unroll
  for (int ks = 0; ks < 4; ++ks)
    af[ks] = *(const bf16x8*)(Ab + (size_t)rowc * NW + ks * 16 + hi * 4);
  gemm_body(af, Wl, lane, blockIdx.x, wave, Bb);
}

// Layer 0: A = x (f32), RNE-packed on the fly (numerics == cvt + gemm).
__global__ __launch_bounds__(512, 4) void k_gemm0(const float* __restrict__ x,
                                                  const u32* __restrict__ Wtb,
                                                  u32* __restrict__ Bb) {
  __shared__ u32 Wl[128 * 64];
  const int t = threadIdx.x;
#pragma unroll
  for (int i = 0; i < 4; ++i) {
    const int idx = (t + i * 512) * 4;
    const uint4 v = *(const uint4*)(Wtb + idx);
    const int byte = idx * 4;
    const int sw = byte ^ (((byte >> 8) & 7) << 4);
    *(uint4*)((char*)Wl + sw) = v;
  }
  __syncthreads();

  const int wave = t >> 6, lane = t & 63;
  const int hi = lane >> 4, lo = lane & 15;
  int row = blockIdx.x * 128 + wave * 16 + lo;
  const int rowc = row < NN ? row : NN - 1;
  const float* xr = x + (size_t)rowc * D;

  bf16x8 af[4];
#pragma unroll
  for (int ks = 0; ks < 4; ++ks) {
    const int d0 = (ks * 16 + hi * 4) * 2;
    const float4 f0 = *(const float4*)(xr + d0);
    const float4 f1 = *(const float4*)(xr + d0 + 4);
    uint4 q;
    q.x = bpack(f0.x, f0.y); q.y = bpack(f0.z, f0.w);
    q.z = bpack(f1.x, f1.y); q.w = bpack(f1.z, f1.w);
    af[ks] = __builtin_bit_cast(bf16x8, q);
  }
  gemm_body(af, Wl, lane, blockIdx.x, wave, Bb);
}

// ---------------- Aggregation: one wave/node, 16-deep SGPR-broadcast gather ----

__device__ __forceinline__ void agg_core(const u32* __restrict__ hwb,
                                         const int* __restrict__ colv,
                                         const unsigned* __restrict__ rowptr,
                                         const float* __restrict__ dinv,
                                         int wid, int lane,
                                         float& ax, float& ay) {
  const float di = dinv[wid];
  const u32 sv = hwb[(size_t)wid * NW + lane];
  ax = blo(sv) * di * di;
  ay = bhi(sv) * di * di;

  const unsigned s = rowptr[wid], e = rowptr[wid + 1];
  const int deg = (int)(e - s);
  const int nl = deg < 64 ? deg : 64;
  const int nlr = (nl + 7) & ~7;       // pad to x8; pad lanes have w=0

  int srcl = wid;
  float wl = 0.f;
  if (lane < nl) {
    srcl = colv[s + lane];
    wl = dinv[srcl] * di;
  }

  int q = 0;
  while (q < nlr) {
    if (q + 16 <= nlr) {
      int sq[16]; float wq[16]; u32 uq[16];
#pragma unroll
      for (int k = 0; k < 16; ++k) {
        sq[k] = __builtin_amdgcn_readlane(srcl, q + k);
        wq[k] = __uint_as_float((u32)__builtin_amdgcn_readlane((int)__float_as_uint(wl), q + k));
      }
#pragma unroll
      for (int k = 0; k < 16; ++k) uq[k] = hwb[(size_t)sq[k] * NW + lane];
#pragma unroll
      for (int k = 0; k < 16; ++k) {
        ax = fmaf(wq[k], blo(uq[k]), ax);
        ay = fmaf(wq[k], bhi(uq[k]), ay);
      }
      q += 16;
    } else {
      int sq[8]; float wq[8]; u32 uq[8];
#pragma unroll
      for (int k = 0; k < 8; ++k) {
        sq[k] = __builtin_amdgcn_readlane(srcl, q + k);
        wq[k] = __uint_as_float((u32)__builtin_amdgcn_readlane((int)__float_as_uint(wl), q + k));
      }
#pragma unroll
      for (int k = 0; k < 8; ++k) uq[k] = hwb[(size_t)sq[k] * NW + lane];
#pragma unroll
      for (int k = 0; k < 8; ++k) {
        ax = fmaf(wq[k], blo(uq[k]), ax);
        ay = fmaf(wq[k], bhi(uq[k]), ay);
      }
      q += 8;
    }
  }
  // rare tail: degree > 64
  for (unsigned j = s + (unsigned)nl; j < e; ++j) {
    const int src = colv[j];
    const float w = dinv[src] * di;
    const u32 u = hwb[(size_t)src * NW + lane];
    ax = fmaf(w, blo(u), ax);
    ay = fmaf(w, bhi(u), ay);
  }
}

__global__ __launch_bounds__(256) void k_agg(const u32* __restrict__ hwb,
                                             const int* __restrict__ colv,
                                             const unsigned* __restrict__ rowptr,
                                             const float* __restrict__ dinv,
                                             const float* __restrict__ bias,
                                             u32* __restrict__ hob) {
  const int widt = (blockIdx.x * 256 + threadIdx.x) >> 6;
  if (widt >= NN) return;
  const int wid = __builtin_amdgcn_readfirstlane(widt);
  const int lane = threadIdx.x & 63;

  float ax, ay;
  agg_core(hwb, colv, rowptr, dinv, wid, lane, ax, ay);

  const float2 b = *(const float2*)&bias[lane * 2];
  ax += b.x; ay += b.y;
  ax = ax > 0.f ? ax : 0.f;
  ay = ay > 0.f ? ay : 0.f;
  hob[(size_t)wid * NW + lane] = bpack(ax, ay);
}

// Last layer: fused head GEMV, f32 accum, no bf16 store of final hidden.
__global__ __launch_bounds__(256) void k_agg_head(const u32* __restrict__ hwb,
                                                  const int* __restrict__ colv,
                                                  const unsigned* __restrict__ rowptr,
                                                  const float* __restrict__ dinv,
                                                  const float* __restrict__ bias,
                                                  const float* __restrict__ hW,
                                                  const float* __restrict__ hbv,
                                                  float* __restrict__ out) {
  const int widt = (blockIdx.x * 256 + threadIdx.x) >> 6;
  if (widt >= NN) return;
  const int wid = __builtin_amdgcn_readfirstlane(widt);
  const int lane = threadIdx.x & 63;

  float ax, ay;
  agg_core(hwb, colv, rowptr, dinv, wid, lane, ax, ay);

  const float2 b = *(const float2*)&bias[lane * 2];
  ax += b.x; ay += b.y;
  ax = ax > 0.f ? ax : 0.f;
  ay = ay > 0.f ? ay : 0.f;

  const float2 w = *(const float2*)&hW[lane * 2];
  float sum = ax * w.x + ay * w.y;
#pragma unroll
  for (int off = 32; off > 0; off >>= 1) sum += __shfl_down(sum, off, 64);
  if (lane == 0) out[wid] = sum + hbv[0];
}

// ---------------- launch ----------------

extern "C" void kernel_launch(void* const* d_in, const int* in_sizes, int n_in,
                              void* d_out, int out_size, void* d_ws, size_t ws_size,
                              hipStream_t stream) {
  const float* x   = (const float*)d_in[0];
  const int*   ei  = (const int*)d_in[1];
  const float* Ws  = (const float*)d_in[2];
  const float* bs  = (const float*)d_in[3];
  const float* hW  = (const float*)d_in[4];
  const float* hb  = (const float*)d_in[5];
  float* out = (float*)d_out;

  char* w = (char*)d_ws;
  u32*      bufA    = (u32*)w;      w += (size_t)NN * NW * 4;        // 25.6 MB (h)
  u32*      bufB    = (u32*)w;      w += (size_t)NN * NW * 4;        // 25.6 MB (hw)
  int*      colv    = (int*)w;      w += (size_t)NE * 4;             // 6.4 MB
  u32*      ebuf    = (u32*)w;      w += (size_t)NE * 4;             // 6.4 MB
  u32*      hist    = (u32*)w;      w += (size_t)NBK * NCH * 4;      // 391 KB
  u32*      Wtb     = (u32*)w;      w += (size_t)NL * 128 * 64 * 4;  // 96 KB
  unsigned* rowptr  = (unsigned*)w; w += (size_t)(NN + 16) * 4;
  float*    dinv    = (float*)w;    w += (size_t)NN * 4;
  u32*      btot    = (u32*)w;      w += (size_t)(NBK + 8) * 4;
  u32*      bkbase  = (u32*)w;      w += (size_t)(NBK + 8) * 4;

  const int* srcv = ei;
  const int* dstv = ei + NE;

  // ---- CSR build (no global scatter) ----
  k_hist   <<<NCH, 256, 0, stream>>>(dstv, hist);
  k_btot   <<<NBK, 256, 0, stream>>>(hist, btot);
  k_bscan  <<<1,   512, 0, stream>>>(btot, bkbase);
  k_cscan  <<<NBK, 256, 0, stream>>>(bkbase, hist);
  k_scatter<<<NCH, 256, 0, stream>>>(srcv, dstv, hist, ebuf);
  k_build  <<<NBK, 256, 0, stream>>>(ebuf, bkbase, colv, rowptr, dinv);

  k_wcvt<<<(NL * 128 * 64 + 255) / 256, 256, 0, stream>>>(Ws, Wtb);

  const int GB = (NN + 127) / 128;   // GEMM blocks (512 thr)
  const int AB = (NN + 3) / 4;       // agg blocks: 4 waves x 1 node

  for (int l = 0; l < NL; ++l) {
    if (l == 0)
      k_gemm0<<<GB, 512, 0, stream>>>(x, Wtb, bufB);
    else
      k_gemm<<<GB, 512, 0, stream>>>(bufA, Wtb + (size_t)l * 128 * 64, bufB);

    if (l < NL - 1) {
      k_agg<<<AB, 256, 0, stream>>>(bufB, colv, rowptr, dinv,
                                    bs + (size_t)l * D, bufA);
    } else {
      k_agg_head<<<AB, 256, 0, stream>>>(bufB, colv, rowptr, dinv,
                                         bs + (size_t)l * D, hW, hb, out);
    }
  }
}